// Round 1
// baseline (189.351 us; speedup 1.0000x reference)
//
#include <hip/hip_runtime.h>

#define VOCAB 50257
#define BEAM  8
#define BSZ   64
#define KSEL  16
#define CHUNK 4
#define TPB   256
#define NCAND (BEAM * CHUNK * KSEL)   // 512 candidate keys per row

// Monotone order-preserving map fp32 -> u32 (and inverse).
__device__ __forceinline__ unsigned int ord32(float f) {
    unsigned int u = __float_as_uint(f);
    return (u & 0x80000000u) ? ~u : (u | 0x80000000u);
}
__device__ __forceinline__ float unord32(unsigned int o) {
    unsigned int u = (o & 0x80000000u) ? (o & 0x7FFFFFFFu) : ~o;
    return __uint_as_float(u);
}

// Key = (ord(value) << 32) | (0xFFFFFFFF - flat_index)
// max-key order == (value desc, flat index asc) == jax lax.top_k tie-breaking.
// Real keys are always > 0 (low 32 bits nonzero since flat < 2^22), so 0 is a
// safe "no candidate" sentinel.

__global__ __launch_bounds__(TPB)
void beam_topk_scan(const float* __restrict__ lprobs,
                    const float* __restrict__ scores,
                    const int*   __restrict__ mask,
                    const int*   __restrict__ stepp,
                    unsigned long long* __restrict__ ws)
{
    const int blk   = blockIdx.x;                 // b*(BEAM*CHUNK) + beam*CHUNK + chunk
    const int chunk = blk % CHUNK;
    const int beam  = (blk / CHUNK) % BEAM;
    const int b     = blk / (CHUNK * BEAM);
    const int tid   = threadIdx.x;
    const int step  = stepp[0];

    unsigned long long* out = ws + (size_t)blk * KSEL;

    const int  bb   = b * BEAM + beam;
    const int* m    = mask + bb * 4;
    const bool keep = (m[0] + m[1] + m[2] + m[3]) == 4;
    const float sadd  = (step == 0) ? 0.0f : scores[bb * 16 + (step - 1)];
    const bool active = (step != 0) || (beam == 0);   // step==0 keeps only beam 0

    if (!active || (!keep && chunk != 0)) {           // no candidates from this block
        if (tid < KSEL) out[tid] = 0ull;
        return;
    }
    if (!keep) {
        // All 50257 values equal sadd -> top-16 = sadd at vocab idx 0..15 (chunk 0).
        if (tid < KSEL) {
            unsigned int flat = (unsigned)(beam * VOCAB + tid);
            out[tid] = ((unsigned long long)ord32(sadd) << 32) | (0xFFFFFFFFu - flat);
        }
        return;
    }

    // ---- scan this chunk of the kept beam ----
    const int per = (VOCAB + CHUNK - 1) / CHUNK;      // 12565
    const int lo  = chunk * per;
    const int hi  = (lo + per < VOCAB) ? (lo + per) : VOCAB;
    const float* base = lprobs + (size_t)bb * VOCAB;
    const unsigned int fbase = (unsigned)(beam * VOCAB);

    // per-thread top-16, ascending (best[0] = current min); register-resident,
    // static indices only (dynamic indexing would spill to scratch).
    unsigned long long best[KSEL];
    #pragma unroll
    for (int i = 0; i < KSEL; ++i) best[i] = 0ull;

    for (int i0 = lo + tid; i0 < hi; i0 += TPB * 4) {
        #pragma unroll
        for (int u = 0; u < 4; ++u) {
            const int i = i0 + u * TPB;
            if (i < hi) {
                const float v = base[i] + sadd;
                const unsigned long long key =
                    ((unsigned long long)ord32(v) << 32) |
                    (0xFFFFFFFFu - (fbase + (unsigned)i));
                if (key > best[0]) {
                    best[0] = key;
                    #pragma unroll
                    for (int j = 0; j < KSEL - 1; ++j) {
                        if (best[j] > best[j + 1]) {
                            unsigned long long t = best[j];
                            best[j] = best[j + 1];
                            best[j + 1] = t;
                        } else break;
                    }
                }
            }
        }
    }

    // ---- block-level k-way merge of 256 sorted lists, extract 16 maxima ----
    __shared__ unsigned long long pool[TPB * KSEL];   // 32 KB
    #pragma unroll
    for (int j = 0; j < KSEL; ++j) pool[tid * KSEL + j] = best[j];

    __shared__ unsigned long long wmax[TPB / 64];
    int ptr = KSEL - 1;
    unsigned long long head = best[KSEL - 1];
    __syncthreads();

    for (int r = 0; r < KSEL; ++r) {
        unsigned long long mx = head;
        #pragma unroll
        for (int off = 32; off > 0; off >>= 1) {
            unsigned long long o = __shfl_down(mx, off);  // wave64
            if (o > mx) mx = o;
        }
        if ((tid & 63) == 0) wmax[tid >> 6] = mx;
        __syncthreads();
        unsigned long long w = wmax[0];
        #pragma unroll
        for (int q = 1; q < TPB / 64; ++q) if (wmax[q] > w) w = wmax[q];
        if (head == w && head != 0ull) {              // keys unique -> single popper
            --ptr;
            head = (ptr >= 0) ? pool[tid * KSEL + ptr] : 0ull;
        }
        if (tid == 0) out[r] = w;
        __syncthreads();
    }
}

__global__ __launch_bounds__(TPB)
void beam_topk_select(const unsigned long long* __restrict__ ws,
                      float* __restrict__ out)
{
    const int b   = blockIdx.x;
    const int tid = threadIdx.x;
    __shared__ unsigned long long keys[NCAND];
    const unsigned long long* src = ws + (size_t)b * NCAND;
    for (int i = tid; i < NCAND; i += TPB) keys[i] = src[i];
    __syncthreads();

    for (int c = tid; c < NCAND; c += TPB) {
        const unsigned long long k0 = keys[c];
        if (k0 == 0ull) continue;                     // sentinel, never top-16
        int rank = 0;
        for (int j = 0; j < NCAND; ++j) rank += (keys[j] > k0) ? 1 : 0;
        if (rank < KSEL) {
            const unsigned int flat = 0xFFFFFFFFu - (unsigned)(k0 & 0xFFFFFFFFull);
            const float val = unord32((unsigned)(k0 >> 32));
            const int vi = (int)(flat % VOCAB);
            const int bi = (int)(flat / VOCAB);
            out[b * KSEL + rank]                   = val;         // scores_buf
            out[BSZ * KSEL + b * KSEL + rank]      = (float)vi;   // indices_buf
            out[2 * BSZ * KSEL + b * KSEL + rank]  = (float)bi;   // beams_buf
        }
    }
}

extern "C" void kernel_launch(void* const* d_in, const int* in_sizes, int n_in,
                              void* d_out, int out_size, void* d_ws, size_t ws_size,
                              hipStream_t stream)
{
    const float* lprobs = (const float*)d_in[0];
    const float* scores = (const float*)d_in[1];
    const int*   mask   = (const int*)d_in[2];
    const int*   stepp  = (const int*)d_in[3];
    float* out = (float*)d_out;
    unsigned long long* ws = (unsigned long long*)d_ws;   // needs 2048*16*8 = 256 KB

    hipLaunchKernelGGL(beam_topk_scan, dim3(BSZ * BEAM * CHUNK), dim3(TPB), 0, stream,
                       lprobs, scores, mask, stepp, ws);
    hipLaunchKernelGGL(beam_topk_select, dim3(BSZ), dim3(TPB), 0, stream, ws, out);
}